// Round 17
// baseline (2344.692 us; speedup 1.0000x reference)
//
#include <hip/hip_runtime.h>
#include <cmath>

#define B_ 64
#define P_ 196
#define ENC_ 2048
#define DEC_ 1024
#define V_ 10000
#define MAXLEN_ 20
#define TDEC_ 19

typedef __attribute__((ext_vector_type(8))) short bf16x8;
typedef __attribute__((ext_vector_type(4))) float f32x4;

// Tiled weight layout: tile = 16 rows x 32 k = 512 bf16 = 1KB, k-tiles fastest.
// element (r,k): offset = ((r>>4)*(K>>5) + (k>>5))*512 + ((r&15) | (((k>>3)&3)<<4))*8 + (k&7)

// ---------------- static device buffers ----------------
__device__ __align__(16) short g_encb[(size_t)12544 * 2048];    // sorted enc, bf16 row-major
__device__ __align__(16) short g_encbt[(size_t)12544 * 2048];   // sorted enc, bf16 TILED
__device__ __align__(16) short g_att1[(size_t)12544 * 1024];    // att1, bf16 (incl. be)
__device__ __align__(16) short g_Wp1t[(size_t)4096 * 2048];     // [Wih1[:, :1024] | Whh1] tiled
__device__ __align__(16) short g_Wemt[(size_t)4096 * 2048];     // Wih1[:, 1024:3072] tiled
__device__ __align__(16) short g_Wembt[(size_t)4096 * 1024];    // Wih1[:, 3072:4096] tiled
__device__ __align__(16) short g_Wc2t[(size_t)4096 * 4096];     // [Wih2(3072)|Whh2(1024)] tiled
__device__ __align__(16) short g_Webt[(size_t)1024 * 2048];     // We tiled
__device__ __align__(16) short g_Wdt[(size_t)1024 * 1024];      // Wd tiled
__device__ __align__(16) short g_Wfc1t[(size_t)10000 * 1024];   // Wfc1 tiled
__device__ __align__(16) short g_Wfct[(size_t)10000 * 1024];    // Wfc tiled
__device__ __align__(16) short g_xs1[(size_t)20 * 64 * 2048];   // per-t [h2|h1] (LSTM1 step A)
__device__ __align__(16) short g_xemb[(size_t)19 * 64 * 1024];  // per-t emb_t
__device__ __align__(16) short g_xc2[(size_t)20 * 64 * 4096];   // per-t [awe|h1|h2]
__device__ __align__(16) short g_em[64 * 2048];                 // enc mean, bf16
__device__ __align__(16) float g_preemb[(size_t)19 * 64 * 4096]; // per-t emb gate part
__device__ __align__(16) float g_preem[64 * 4096];               // em gate part
__device__ __align__(16) float g_part[(size_t)16 * 64 * 4096];
__device__ __align__(16) float g_att2p[(size_t)8 * 64 * 1024];
__device__ __align__(16) float g_c1[64 * 1024];
__device__ __align__(16) float g_c2[64 * 1024];
__device__ int g_ibuf[64 + 64 + 64 * MAXLEN_];

__device__ __forceinline__ short f2b(float f) {
  unsigned u = __float_as_uint(f);
  u += 0x7FFFu + ((u >> 16) & 1u);
  return (short)(u >> 16);
}
__device__ __forceinline__ float b2f(short s) {
  return __uint_as_float(((unsigned)(unsigned short)s) << 16);
}

// ---------------- sort + int-ish outputs ----------------
__global__ void k_sort(const int* __restrict__ cl_in, const int* __restrict__ caps_in,
                       int* __restrict__ sind, int* __restrict__ declen, int* __restrict__ caps_s,
                       float* __restrict__ out_caps, float* __restrict__ out_declen,
                       float* __restrict__ out_sind) {
  int i = threadIdx.x;  // 64 threads
  __shared__ int cl[B_];
  cl[i] = cl_in[i];
  __syncthreads();
  int my = cl[i], pos = 0;
  for (int j = 0; j < B_; ++j) {
    int cj = cl[j];
    if (cj > my || (cj == my && j < i)) pos++;
  }
  sind[pos] = i;
  __syncthreads();
  int sb = sind[i];
  int dl = cl[sb] - 1;
  declen[i] = dl;
  out_declen[i] = (float)dl;
  out_sind[i] = (float)sb;
  for (int t = 0; t < MAXLEN_; ++t) {
    int v = caps_in[sb * MAXLEN_ + t];
    caps_s[i * MAXLEN_ + t] = v;
    out_caps[i * MAXLEN_ + t] = (float)v;
  }
}

// gather-sort + fp32->bf16 encoder: row-major AND tiled copies
__global__ __launch_bounds__(256) void k_encprep(const float* __restrict__ enc,
                                                 const int* __restrict__ sind,
                                                 short* __restrict__ encb,
                                                 short* __restrict__ encbt) {
  int mg = blockIdx.x;  // 12544
  int b = mg / P_, p = mg - b * P_;
  int tid = threadIdx.x;
  const float* src = enc + ((size_t)sind[b] * P_ + p) * ENC_ + tid * 8;
  float4 a = *(const float4*)src;
  float4 c = *(const float4*)(src + 4);
  bf16x8 v;
  v[0] = f2b(a.x); v[1] = f2b(a.y); v[2] = f2b(a.z); v[3] = f2b(a.w);
  v[4] = f2b(c.x); v[5] = f2b(c.y); v[6] = f2b(c.z); v[7] = f2b(c.w);
  *(bf16x8*)(encb + (size_t)mg * ENC_ + tid * 8) = v;
  size_t off = (((size_t)(mg >> 4) * 64 + (tid >> 2)) << 9) +
               (((mg & 15) | ((tid & 3) << 4)) << 3);
  *(bf16x8*)(encbt + off) = v;
}

// enc mean -> g_em (bf16), grid (64, 4): 512-col chunks
__global__ __launch_bounds__(64) void k_encmeanb(const short* __restrict__ encb,
                                                 short* __restrict__ em) {
  int b = blockIdx.x;
  int col0 = blockIdx.y * 512 + threadIdx.x * 8;
  const short* src = encb + (size_t)b * P_ * ENC_ + col0;
  float acc[8] = {};
  for (int p = 0; p < P_; ++p) {
    bf16x8 v = *(const bf16x8*)(src + (size_t)p * ENC_);
#pragma unroll
    for (int j = 0; j < 8; ++j) acc[j] += b2f(v[j]);
  }
#pragma unroll
  for (int j = 0; j < 8; ++j) em[b * 2048 + col0 + j] = f2b(acc[j] * (1.0f / 196.0f));
}

// prefill xemb[t][b] = emb table row of caps[b][t]
__global__ __launch_bounds__(256) void k_prefill(const float* __restrict__ emb,
                                                 const int* __restrict__ caps_s,
                                                 short* __restrict__ xemb) {
  int t = blockIdx.x, b = blockIdx.y, tid = threadIdx.x;  // (19, 64)
  short* xr = xemb + ((size_t)t * 64 + b) * 1024;
  int cap = caps_s[b * MAXLEN_ + t];
  int j = tid * 4;
  float4 v = *(const float4*)(emb + (size_t)cap * 1024 + j);
  short4 o;
  o.x = f2b(v.x); o.y = f2b(v.y); o.z = f2b(v.z); o.w = f2b(v.w);
  *(short4*)(xr + j) = o;
}

// ---------------- fused weight converts: all 10 jobs, wave-per-tile, coalesced 1KB writes ----------------
struct F2BJobs {
  const float* src[10];
  short* dst[10];
  int kstride[10];
  int c0[10];
  int ncols[10];
  int ktot[10];
  int koff[10];
  int base[11];  // cumulative block offsets (1 block = 4 tiles = 2048 elems)
};

__global__ __launch_bounds__(256) void k_f2bt_all(F2BJobs jb) {
  int bg = blockIdx.x;
  int j = 0;
#pragma unroll
  for (int q = 1; q < 10; ++q)
    if (bg >= jb.base[q]) j = q;
  int wave = threadIdx.x >> 6, lane = threadIdx.x & 63;
  int tau = (bg - jb.base[j]) * 4 + wave;       // tile index within job
  int ntk = jb.ncols[j] >> 5;                    // k-tiles per row-group (job-local)
  int rt = tau / ntk, kt = tau - rt * ntk;
  int r = rt * 16 + (lane & 15);                 // source row
  int k8 = kt * 32 + (lane >> 4) * 8;            // source k (job-local)
  const float* s = jb.src[j] + (size_t)r * jb.kstride[j] + jb.c0[j] + k8;
  float4 a = *(const float4*)s;
  float4 c = *(const float4*)(s + 4);
  bf16x8 v;
  v[0] = f2b(a.x); v[1] = f2b(a.y); v[2] = f2b(a.z); v[3] = f2b(a.w);
  v[4] = f2b(c.x); v[5] = f2b(c.y); v[6] = f2b(c.z); v[7] = f2b(c.w);
  int kg0 = jb.koff[j] + kt * 32;                // global k of tile start
  size_t toff = (((size_t)rt * (jb.ktot[j] >> 5) + (kg0 >> 5)) << 9);
  *(bf16x8*)(jb.dst[j] + toff + lane * 8) = v;   // wave writes one contiguous 1KB tile
}

// ---------------- att1 = enc @ We^T + be -> bf16 (12544x1024), both TILED ----------------
// Round-10 measured-best config: 512 thr, wave = 4mt x 4nt, block 128x256, grid (98,4), no swizzle
__global__ __launch_bounds__(512) void k_att1_t(const short* __restrict__ At,
                                                const short* __restrict__ Wt,
                                                const float* __restrict__ be,
                                                short* __restrict__ Cb) {
  int wave = threadIdx.x >> 6, lane = threadIdx.x & 63;
  int mt0 = blockIdx.x * 8 + (wave >> 2) * 4;
  int nt0 = blockIdx.y * 16 + (wave & 3) * 4;
  f32x4 acc[4][4] = {};
  const short* Ab = At + ((size_t)mt0 * 64 << 9) + lane * 8;  // ntk = 64
  const short* Wb = Wt + ((size_t)nt0 * 64 << 9) + lane * 8;
  for (int kt = 0; kt < 64; ++kt) {
    bf16x8 a[4], b[4];
#pragma unroll
    for (int i = 0; i < 4; ++i) a[i] = *(const bf16x8*)(Ab + (((size_t)i * 64 + kt) << 9));
#pragma unroll
    for (int j = 0; j < 4; ++j) b[j] = *(const bf16x8*)(Wb + (((size_t)j * 64 + kt) << 9));
#pragma unroll
    for (int i = 0; i < 4; ++i)
#pragma unroll
      for (int j = 0; j < 4; ++j)
        acc[i][j] = __builtin_amdgcn_mfma_f32_16x16x32_bf16(a[i], b[j], acc[i][j], 0, 0, 0);
  }
  int rr = (lane >> 4) * 4, cc = lane & 15;
  int m0 = mt0 * 16, n0 = nt0 * 16;
#pragma unroll
  for (int i = 0; i < 4; ++i)
#pragma unroll
    for (int j = 0; j < 4; ++j) {
      int n = n0 + j * 16 + cc;
      float bn = be[n];
#pragma unroll
      for (int r = 0; r < 4; ++r) {
        int m = m0 + i * 16 + rr + r;
        Cb[(size_t)m * 1024 + n] = f2b(acc[i][j][r] + bn);
      }
    }
}

// ---------------- skinny MFMA GEMM, tiled W: part[s][64][N] ----------------
__global__ __launch_bounds__(256) void k_skinny_t(const short* __restrict__ A, int lda,
                                                  const short* __restrict__ Wt, int ldw,
                                                  int N, int kchunk, float* __restrict__ part) {
  int wave = threadIdx.x >> 6, lane = threadIdx.x & 63;
  int n0 = blockIdx.x * 128 + wave * 32;
  int kb = blockIdx.y * kchunk;
  int lr = lane & 15, lk = (lane >> 4) * 8;
  int ntk = ldw >> 5;
  int nt0 = n0 >> 4;
  f32x4 acc[4][2] = {};
  const short* Ab = A + (size_t)lr * lda + kb + lk;
  const short* Wb0 = Wt + (((size_t)nt0 * ntk + (kb >> 5)) << 9) + lane * 8;
  const short* Wb1 = Wt + (((size_t)(nt0 + 1) * ntk + (kb >> 5)) << 9) + lane * 8;
  int nkt = kchunk >> 5;
  for (int kt = 0; kt < nkt; ++kt) {
    bf16x8 a[4], b0, b1;
#pragma unroll
    for (int i = 0; i < 4; ++i) a[i] = *(const bf16x8*)(Ab + (size_t)i * 16 * lda + kt * 32);
    b0 = *(const bf16x8*)(Wb0 + ((size_t)kt << 9));
    b1 = *(const bf16x8*)(Wb1 + ((size_t)kt << 9));
#pragma unroll
    for (int i = 0; i < 4; ++i) {
      acc[i][0] = __builtin_amdgcn_mfma_f32_16x16x32_bf16(a[i], b0, acc[i][0], 0, 0, 0);
      acc[i][1] = __builtin_amdgcn_mfma_f32_16x16x32_bf16(a[i], b1, acc[i][1], 0, 0, 0);
    }
  }
  float* po = part + (size_t)blockIdx.y * 64 * N;
  int rr = (lane >> 4) * 4, cc = lane & 15;
#pragma unroll
  for (int i = 0; i < 4; ++i)
#pragma unroll
    for (int j = 0; j < 2; ++j) {
      int n = n0 + j * 16 + cc;
#pragma unroll
      for (int r = 0; r < 4; ++r) {
        int m = i * 16 + rr + r;
        po[(size_t)m * N + n] = acc[i][j][r];
      }
    }
}

// sum nsplit partial planes into dst (64*4096 elems)
__global__ void k_sumn(const float* __restrict__ part, int nsplit, float* __restrict__ dst) {
  int idx = blockIdx.x * 256 + threadIdx.x;
  float s = 0.0f;
  for (int q = 0; q < nsplit; ++q) s += part[(size_t)q * 64 * 4096 + idx];
  dst[idx] = s;
}

// ---------------- batched emb GEMM: preemb[t][64][4096] = xemb[t] @ Wemb^T (K=1024) ----------------
// 1-D grid 304 = 8*38, XCD-chunk swizzle: XCD owns 2 W n-slices x all 19 t.
__global__ __launch_bounds__(256) void k_mid_emb4(const short* __restrict__ xemb,
                                                  const short* __restrict__ Wt,
                                                  float* __restrict__ preemb) {
  int wg = blockIdx.x;               // 304 = 8 * 38
  wg = (wg & 7) * 38 + (wg >> 3);
  int t = wg % 19;
  int nch = wg / 19;                 // [0,16)
  const short* A = xemb + (size_t)t * 64 * 1024;
  int wave = threadIdx.x >> 6, lane = threadIdx.x & 63;
  int nt0 = nch * 16 + wave * 4;  // 256 n-tiles total
  int lr = lane & 15, lk = (lane >> 4) * 8;
  f32x4 acc[4][4] = {};
  const short* Ab = A + (size_t)lr * 1024 + lk;
  const short* Wb[4];
#pragma unroll
  for (int j = 0; j < 4; ++j) Wb[j] = Wt + ((size_t)(nt0 + j) * 32 << 9) + lane * 8;
  for (int kt = 0; kt < 32; ++kt) {
    bf16x8 a[4], b[4];
#pragma unroll
    for (int j = 0; j < 4; ++j) b[j] = *(const bf16x8*)(Wb[j] + ((size_t)kt << 9));
#pragma unroll
    for (int i = 0; i < 4; ++i) a[i] = *(const bf16x8*)(Ab + (size_t)i * 16 * 1024 + kt * 32);
#pragma unroll
    for (int i = 0; i < 4; ++i)
#pragma unroll
      for (int j = 0; j < 4; ++j)
        acc[i][j] = __builtin_amdgcn_mfma_f32_16x16x32_bf16(a[i], b[j], acc[i][j], 0, 0, 0);
  }
  float* po = preemb + (size_t)t * 64 * 4096;
  int rr = (lane >> 4) * 4, cc = lane & 15;
#pragma unroll
  for (int i = 0; i < 4; ++i)
#pragma unroll
    for (int j = 0; j < 4; ++j) {
      int n = (nt0 + j) * 16 + cc;
#pragma unroll
      for (int r = 0; r < 4; ++r) {
        int m = i * 16 + rr + r;
        po[(size_t)m * 4096 + n] = acc[i][j][r];
      }
    }
}

// ---------------- LSTM gates: biases + nsplit partials (+ pre, pre2), update c, forward h ----------------
__global__ void k_gates(const float* __restrict__ part, int nsplit,
                        const float* __restrict__ pre, const float* __restrict__ pre2,
                        const float* __restrict__ bih, const float* __restrict__ bhh,
                        float* __restrict__ c,
                        const short* __restrict__ hold, int ldo,
                        short* __restrict__ dst1, int ld1,
                        short* __restrict__ dst2, int ld2,
                        const int* __restrict__ declen, int t) {
  int idx = blockIdx.x * 256 + threadIdx.x;  // 65536
  int b = idx >> 10, j = idx & 1023;
  const float* pb = part + (size_t)b * 4096;
  float gi = bih[j] + bhh[j];
  float gf = bih[1024 + j] + bhh[1024 + j];
  float gg = bih[2048 + j] + bhh[2048 + j];
  float go = bih[3072 + j] + bhh[3072 + j];
  if (pre) {
    const float* pp = pre + (size_t)b * 4096;
    gi += pp[j]; gf += pp[j + 1024]; gg += pp[j + 2048]; go += pp[j + 3072];
  }
  if (pre2) {
    const float* pp = pre2 + (size_t)b * 4096;
    gi += pp[j]; gf += pp[j + 1024]; gg += pp[j + 2048]; go += pp[j + 3072];
  }
  for (int s = 0; s < nsplit; ++s) {
    const float* p = pb + (size_t)s * 64 * 4096;
    gi += p[j]; gf += p[j + 1024]; gg += p[j + 2048]; go += p[j + 3072];
  }
  float si = 1.0f / (1.0f + expf(-gi));
  float sf = 1.0f / (1.0f + expf(-gf));
  float so = 1.0f / (1.0f + expf(-go));
  float cn = sf * c[idx] + si * tanhf(gg);
  float hn = so * tanhf(cn);
  short hb;
  if (t < declen[b]) {
    c[idx] = cn;
    hb = f2b(hn);
  } else {
    hb = hold[b * ldo + j];
  }
  dst1[b * ld1 + j] = hb;
  dst2[b * ld2 + j] = hb;
}

// ---------------- fused attention tail: e-scores + softmax + awe, one block per b ----------------
__global__ __launch_bounds__(256) void k_esawe(const short* __restrict__ att1,
                                               const float* __restrict__ att2p,
                                               const float* __restrict__ bd,
                                               const float* __restrict__ Wf,
                                               const float* __restrict__ bf,
                                               const short* __restrict__ encb,
                                               short* __restrict__ xc2t) {
  int b = blockIdx.x;
  __shared__ float a2[1024];
  __shared__ float wfs[1024];
  __shared__ float al[P_];
  int tid = threadIdx.x;
  int wave = tid >> 6, lane = tid & 63;
  // phase A: att2 row (sum 4 K-split partials + bd) and Wf into LDS
  for (int i = tid; i < 1024; i += 256) {
    float s = bd[i];
#pragma unroll
    for (int q = 0; q < 4; ++q) s += att2p[q * 65536 + b * 1024 + i];
    a2[i] = s;
    wfs[i] = Wf[i];
  }
  __syncthreads();
  // phase B: e-scores, 4 waves x 49 p
  float bf0 = bf[0];
  for (int q = 0; q < 49; ++q) {
    int p = wave * 49 + q;
    const short* a1 = att1 + ((size_t)(b * P_ + p)) * 1024;
    float s = 0.0f;
#pragma unroll
    for (int h = 0; h < 2; ++h) {
      int k0 = lane * 8 + h * 512;
      bf16x8 v = *(const bf16x8*)(a1 + k0);
#pragma unroll
      for (int j = 0; j < 8; ++j) s += wfs[k0 + j] * fmaxf(b2f(v[j]) + a2[k0 + j], 0.0f);
    }
#pragma unroll
    for (int off = 32; off; off >>= 1) s += __shfl_down(s, off);
    if (lane == 0) al[p] = s + bf0;
  }
  __syncthreads();
  // phase C: softmax over al[0..195] (wave 0)
  if (tid < 64) {
    float vals[4];
    float mx = -1e30f;
#pragma unroll
    for (int q = 0; q < 4; ++q) {
      int p = tid + q * 64;
      vals[q] = (p < P_) ? al[p] : -1e30f;
      mx = fmaxf(mx, vals[q]);
    }
#pragma unroll
    for (int off = 32; off; off >>= 1) mx = fmaxf(mx, __shfl_xor(mx, off));
    float sum = 0.0f;
#pragma unroll
    for (int q = 0; q < 4; ++q) {
      int p = tid + q * 64;
      vals[q] = (p < P_) ? expf(vals[q] - mx) : 0.0f;
      sum += vals[q];
    }
#pragma unroll
    for (int off = 32; off; off >>= 1) sum += __shfl_xor(sum, off);
    float inv = 1.0f / sum;
#pragma unroll
    for (int q = 0; q < 4; ++q) {
      int p = tid + q * 64;
      if (p < P_) al[p] = vals[q] * inv;
    }
  }
  __syncthreads();
  // phase D: awe cols, each thread owns 8 contiguous cols
  int col = tid * 8;
  const short* src = encb + (size_t)b * P_ * ENC_ + col;
  float acc[8] = {};
#pragma unroll 4
  for (int p = 0; p < P_; ++p) {
    bf16x8 v = *(const bf16x8*)(src + (size_t)p * ENC_);
    float ap = al[p];
#pragma unroll
    for (int j = 0; j < 8; ++j) acc[j] += ap * b2f(v[j]);
  }
  bf16x8 o;
#pragma unroll
  for (int j = 0; j < 8; ++j) o[j] = f2b(acc[j]);
  *(bf16x8*)(xc2t + b * 4096 + col) = o;
}

// ---------------- batched head GEMM: 4 nt per wave, 1-D grid 760 = 8*95 XCD-chunked ----------------
__global__ __launch_bounds__(256) void k_head4(const short* __restrict__ Aall,
                                               const short* __restrict__ Wt,
                                               const float* __restrict__ bias,
                                               float* __restrict__ outp,
                                               const int* __restrict__ declen) {
  int wg = blockIdx.x;               // 760 = 8 * 95
  wg = (wg & 7) * 95 + (wg >> 3);
  int t = wg % 19;
  int nch = wg / 19;                 // [0,40)
  const short* A = Aall + (size_t)t * (64 * 4096);
  int wave = threadIdx.x >> 6, lane = threadIdx.x & 63;
  int nt0 = nch * 16 + wave * 4;     // 4 n-tiles per wave; 625 total
  int lr = lane & 15, lk = (lane >> 4) * 8;
  f32x4 acc[4][4] = {};
  const short* Ab = A + (size_t)lr * 4096 + lk;
  const short* Wb[4];
  bool ok[4];
#pragma unroll
  for (int j = 0; j < 4; ++j) {
    ok[j] = (nt0 + j) < (V_ >> 4);
    Wb[j] = Wt + ((size_t)(ok[j] ? nt0 + j : 0) * 32 << 9) + lane * 8;
  }
  for (int kt = 0; kt < 32; ++kt) {
    bf16x8 a[4], b[4];
#pragma unroll
    for (int j = 0; j < 4; ++j) b[j] = *(const bf16x8*)(Wb[j] + ((size_t)kt << 9));
#pragma unroll
    for (int i = 0; i < 4; ++i) a[i] = *(const bf16x8*)(Ab + (size_t)i * 16 * 4096 + kt * 32);
#pragma unroll
    for (int i = 0; i < 4; ++i)
#pragma unroll
      for (int j = 0; j < 4; ++j)
        acc[i][j] = __builtin_amdgcn_mfma_f32_16x16x32_bf16(a[i], b[j], acc[i][j], 0, 0, 0);
  }
  int rr = (lane >> 4) * 4, cc = lane & 15;
#pragma unroll
  for (int j = 0; j < 4; ++j) {
    if (!ok[j]) continue;
    int n = (nt0 + j) * 16 + cc;
    float bn = bias[n];
#pragma unroll
    for (int i = 0; i < 4; ++i) {
#pragma unroll
      for (int r = 0; r < 4; ++r) {
        int b = i * 16 + rr + r;
        float val = acc[i][j][r] + bn;
        outp[((size_t)b * TDEC_ + t) * V_ + n] = (t < declen[b]) ? val : 0.0f;
      }
    }
  }
}

// ---------------- host ----------------
extern "C" void kernel_launch(void* const* d_in, const int* in_sizes, int n_in,
                              void* d_out, int out_size, void* d_ws, size_t ws_size,
                              hipStream_t stream) {
  (void)in_sizes; (void)n_in; (void)d_ws; (void)ws_size; (void)out_size;
  const float* enc  = (const float*)d_in[0];
  const int*   caps = (const int*)d_in[1];
  const int*   cl   = (const int*)d_in[2];
  const float* emb  = (const float*)d_in[3];
  const float* We   = (const float*)d_in[4];
  const float* be   = (const float*)d_in[5];
  const float* Wd   = (const float*)d_in[6];
  const float* bd   = (const float*)d_in[7];
  const float* Wf   = (const float*)d_in[8];
  const float* bf   = (const float*)d_in[9];
  const float* Wih1 = (const float*)d_in[10];
  const float* Whh1 = (const float*)d_in[11];
  const float* bih1 = (const float*)d_in[12];
  const float* bhh1 = (const float*)d_in[13];
  const float* Wih2 = (const float*)d_in[14];
  const float* Whh2 = (const float*)d_in[15];
  const float* bih2 = (const float*)d_in[16];
  const float* bhh2 = (const float*)d_in[17];
  const float* Wfc1 = (const float*)d_in[18];
  const float* bfc1 = (const float*)d_in[19];
  const float* Wfc  = (const float*)d_in[20];
  const float* bfc  = (const float*)d_in[21];
  float* out = (float*)d_out;

  short *encb, *encbt, *att1, *Wp1t, *Wemt, *Wembt, *Wc2t, *Webt, *Wdt, *Wfc1t, *Wfct;
  short *xs1, *xemb, *xc2, *em;
  float *preemb, *preem, *part, *att2p, *c1, *c2;
  int* ib;
  hipGetSymbolAddress((void**)&encb, HIP_SYMBOL(g_encb));
  hipGetSymbolAddress((void**)&encbt, HIP_SYMBOL(g_encbt));
  hipGetSymbolAddress((void**)&att1, HIP_SYMBOL(g_att1));
  hipGetSymbolAddress((void**)&Wp1t, HIP_SYMBOL(g_Wp1t));
  hipGetSymbolAddress((void**)&Wemt, HIP_SYMBOL(g_Wemt));
  hipGetSymbolAddress((void**)&Wembt, HIP_SYMBOL(g_Wembt));
  hipGetSymbolAddress((void**)&Wc2t, HIP_SYMBOL(g_Wc2t));
  hipGetSymbolAddress((void**)&Webt, HIP_SYMBOL(g_Webt));
  hipGetSymbolAddress((void**)&Wdt, HIP_SYMBOL(g_Wdt));
  hipGetSymbolAddress((void**)&Wfc1t, HIP_SYMBOL(g_Wfc1t));
  hipGetSymbolAddress((void**)&Wfct, HIP_SYMBOL(g_Wfct));
  hipGetSymbolAddress((void**)&xs1, HIP_SYMBOL(g_xs1));
  hipGetSymbolAddress((void**)&xemb, HIP_SYMBOL(g_xemb));
  hipGetSymbolAddress((void**)&xc2, HIP_SYMBOL(g_xc2));
  hipGetSymbolAddress((void**)&em, HIP_SYMBOL(g_em));
  hipGetSymbolAddress((void**)&preemb, HIP_SYMBOL(g_preemb));
  hipGetSymbolAddress((void**)&preem, HIP_SYMBOL(g_preem));
  hipGetSymbolAddress((void**)&part, HIP_SYMBOL(g_part));
  hipGetSymbolAddress((void**)&att2p, HIP_SYMBOL(g_att2p));
  hipGetSymbolAddress((void**)&c1, HIP_SYMBOL(g_c1));
  hipGetSymbolAddress((void**)&c2, HIP_SYMBOL(g_c2));
  hipGetSymbolAddress((void**)&ib, HIP_SYMBOL(g_ibuf));
  int* sind = ib;
  int* declen = ib + 64;
  int* caps_s = ib + 128;

  float* out_preds  = out;
  float* out_preds1 = out + (size_t)B_ * TDEC_ * V_;
  float* out_caps   = out + 2ull * B_ * TDEC_ * V_;
  float* out_declen = out_caps + B_ * MAXLEN_;
  float* out_sind   = out_declen + B_;

  // ---- preprocessing ----
  k_sort<<<1, 64, 0, stream>>>(cl, caps, sind, declen, caps_s, out_caps, out_declen, out_sind);
  hipMemsetAsync(c1, 0, 64 * 1024 * sizeof(float), stream);
  hipMemsetAsync(c2, 0, 64 * 1024 * sizeof(float), stream);
  hipMemsetAsync(xs1, 0, (size_t)64 * 2048 * sizeof(short), stream);  // t=0
  hipMemsetAsync(xc2, 0, (size_t)64 * 4096 * sizeof(short), stream);  // t=0
  k_encprep<<<12544, 256, 0, stream>>>(enc, sind, encb, encbt);
  k_encmeanb<<<dim3(64, 4), 64, 0, stream>>>(encb, em);
  k_prefill<<<dim3(19, 64), 256, 0, stream>>>(emb, caps_s, xemb);
  // fused weight converts (10 jobs, one launch, wave-per-tile)
  {
    F2BJobs jb;
    const float* srcs[10] = {Wih1, Whh1, Wih1, Wih1, Wih2, Whh2, We, Wd, Wfc1, Wfc};
    short* dsts[10] = {Wp1t, Wp1t, Wemt, Wembt, Wc2t, Wc2t, Webt, Wdt, Wfc1t, Wfct};
    int kstride[10] = {4096, 1024, 4096, 4096, 3072, 1024, 2048, 1024, 1024, 1024};
    int c0s[10]     = {0, 0, 1024, 3072, 0, 0, 0, 0, 0, 0};
    int ncols[10]   = {1024, 1024, 2048, 1024, 3072, 1024, 2048, 1024, 1024, 1024};
    int ktots[10]   = {2048, 2048, 2048, 1024, 4096, 4096, 2048, 1024, 1024, 1024};
    int koffs[10]   = {0, 1024, 0, 0, 0, 3072, 0, 0, 0, 0};
    int nblk[10]    = {2048, 2048, 4096, 2048, 6144, 2048, 1024, 512, 5000, 5000};
    int cum = 0;
    for (int q = 0; q < 10; ++q) {
      jb.src[q] = srcs[q]; jb.dst[q] = dsts[q];
      jb.kstride[q] = kstride[q]; jb.c0[q] = c0s[q]; jb.ncols[q] = ncols[q];
      jb.ktot[q] = ktots[q]; jb.koff[q] = koffs[q];
      jb.base[q] = cum; cum += nblk[q];
    }
    jb.base[10] = cum;  // 29968
    k_f2bt_all<<<cum, 256, 0, stream>>>(jb);
  }
  k_att1_t<<<dim3(98, 4), 512, 0, stream>>>(encbt, Webt, be, att1);
  // em contribution to LSTM1 gates (once): em @ Wem^T, KS=4, then sum
  k_skinny_t<<<dim3(32, 4), 256, 0, stream>>>(em, 2048, Wemt, 2048, 4096, 512, part);
  k_sumn<<<1024, 256, 0, stream>>>(part, 4, preem);
  // emb contribution per t (batched)
  k_mid_emb4<<<304, 256, 0, stream>>>(xemb, Wembt, preemb);

  // ---- decode loop (6 launches/step) ----
  for (int t = 0; t < TDEC_; ++t) {
    short* s1t = xs1 + (size_t)t * 64 * 2048;
    short* s1n = xs1 + (size_t)(t + 1) * 64 * 2048;
    short* x2t = xc2 + (size_t)t * 64 * 4096;
    short* x2n = xc2 + (size_t)(t + 1) * 64 * 4096;
    // LSTM1 step: [h2|h1] @ Wp1^T  (K=2048, KS=8 -> 256)
    k_skinny_t<<<dim3(32, 8), 256, 0, stream>>>(s1t, 2048, Wp1t, 2048, 4096, 256, part);
    k_gates<<<256, 256, 0, stream>>>(part, 8, preemb + (size_t)t * 64 * 4096, preem,
                                     bih1, bhh1, c1, s1t + 1024, 2048,
                                     s1n + 1024, 2048, x2t + 2048, 4096, declen, t);
    // att2 = h1 @ Wd^T  (K=1024, KS=4 -> 256)
    k_skinny_t<<<dim3(8, 4), 256, 0, stream>>>(x2t + 2048, 4096, Wdt, 1024, 1024, 256, att2p);
    // fused e + softmax + awe (intra-block deps only)
    k_esawe<<<64, 256, 0, stream>>>(att1, att2p, bd, Wf, bf, encb, x2t);
    // LSTM2: [awe|h1|h2] @ Wc2^T  (K=4096, KS=8 -> 512)
    k_skinny_t<<<dim3(32, 8), 256, 0, stream>>>(x2t, 4096, Wc2t, 4096, 4096, 512, part);
    k_gates<<<256, 256, 0, stream>>>(part, 8, nullptr, nullptr, bih2, bhh2, c2, s1t, 2048,
                                     s1n, 2048, x2n + 3072, 4096, declen, t);
  }
  // ---- batched output heads over all t ----
  k_head4<<<760, 256, 0, stream>>>(xc2 + 2048, Wfc1t, bfc1, out_preds1, declen);
  k_head4<<<760, 256, 0, stream>>>(xc2 + 64 * 4096 + 3072, Wfct, bfc, out_preds, declen);
}

// Round 18
// 1695.709 us; speedup vs baseline: 1.3827x; 1.3827x over previous
//
#include <hip/hip_runtime.h>
#include <cmath>

#define B_ 64
#define P_ 196
#define ENC_ 2048
#define DEC_ 1024
#define V_ 10000
#define MAXLEN_ 20
#define TDEC_ 19

typedef __attribute__((ext_vector_type(8))) short bf16x8;
typedef __attribute__((ext_vector_type(4))) float f32x4;

// Tiled weight layout: tile = 16 rows x 32 k = 512 bf16 = 1KB, k-tiles fastest.
// element (r,k): offset = ((r>>4)*(K>>5) + (k>>5))*512 + ((r&15) | (((k>>3)&3)<<4))*8 + (k&7)

// ---------------- static device buffers ----------------
__device__ __align__(16) short g_encb[(size_t)12544 * 2048];    // sorted enc, bf16 row-major
__device__ __align__(16) short g_encbt[(size_t)12544 * 2048];   // sorted enc, bf16 TILED
__device__ __align__(16) short g_att1[(size_t)12544 * 1024];    // att1, bf16 (incl. be)
__device__ __align__(16) short g_Wp1t[(size_t)4096 * 2048];     // [Wih1[:, :1024] | Whh1] tiled
__device__ __align__(16) short g_Wemt[(size_t)4096 * 2048];     // Wih1[:, 1024:3072] tiled
__device__ __align__(16) short g_Wembt[(size_t)4096 * 1024];    // Wih1[:, 3072:4096] tiled
__device__ __align__(16) short g_Wc2t[(size_t)4096 * 4096];     // [Wih2(3072)|Whh2(1024)] tiled
__device__ __align__(16) short g_Webt[(size_t)1024 * 2048];     // We tiled
__device__ __align__(16) short g_Wdt[(size_t)1024 * 1024];      // Wd tiled
__device__ __align__(16) short g_Wfc1t[(size_t)10000 * 1024];   // Wfc1 tiled
__device__ __align__(16) short g_Wfct[(size_t)10000 * 1024];    // Wfc tiled
__device__ __align__(16) short g_xs1[(size_t)20 * 64 * 2048];   // per-t [h2|h1] (LSTM1 step A)
__device__ __align__(16) short g_xemb[(size_t)19 * 64 * 1024];  // per-t emb_t
__device__ __align__(16) short g_xc2[(size_t)20 * 64 * 4096];   // per-t [awe|h1|h2]
__device__ __align__(16) short g_em[64 * 2048];                 // enc mean, bf16
__device__ __align__(16) float g_preemb[(size_t)19 * 64 * 4096]; // per-t emb gate part
__device__ __align__(16) float g_preem[64 * 4096];               // em gate part
__device__ __align__(16) float g_part[(size_t)16 * 64 * 4096];
__device__ __align__(16) float g_att2p[(size_t)8 * 64 * 1024];
__device__ __align__(16) float g_e[64 * P_];
__device__ __align__(16) float g_c1[64 * 1024];
__device__ __align__(16) float g_c2[64 * 1024];
__device__ int g_ibuf[64 + 64 + 64 * MAXLEN_];

__device__ __forceinline__ short f2b(float f) {
  unsigned u = __float_as_uint(f);
  u += 0x7FFFu + ((u >> 16) & 1u);
  return (short)(u >> 16);
}
__device__ __forceinline__ float b2f(short s) {
  return __uint_as_float(((unsigned)(unsigned short)s) << 16);
}

// ---------------- sort + int-ish outputs ----------------
__global__ void k_sort(const int* __restrict__ cl_in, const int* __restrict__ caps_in,
                       int* __restrict__ sind, int* __restrict__ declen, int* __restrict__ caps_s,
                       float* __restrict__ out_caps, float* __restrict__ out_declen,
                       float* __restrict__ out_sind) {
  int i = threadIdx.x;  // 64 threads
  __shared__ int cl[B_];
  cl[i] = cl_in[i];
  __syncthreads();
  int my = cl[i], pos = 0;
  for (int j = 0; j < B_; ++j) {
    int cj = cl[j];
    if (cj > my || (cj == my && j < i)) pos++;
  }
  sind[pos] = i;
  __syncthreads();
  int sb = sind[i];
  int dl = cl[sb] - 1;
  declen[i] = dl;
  out_declen[i] = (float)dl;
  out_sind[i] = (float)sb;
  for (int t = 0; t < MAXLEN_; ++t) {
    int v = caps_in[sb * MAXLEN_ + t];
    caps_s[i * MAXLEN_ + t] = v;
    out_caps[i * MAXLEN_ + t] = (float)v;
  }
}

// gather-sort + fp32->bf16 encoder: row-major AND tiled copies
__global__ __launch_bounds__(256) void k_encprep(const float* __restrict__ enc,
                                                 const int* __restrict__ sind,
                                                 short* __restrict__ encb,
                                                 short* __restrict__ encbt) {
  int mg = blockIdx.x;  // 12544
  int b = mg / P_, p = mg - b * P_;
  int tid = threadIdx.x;
  const float* src = enc + ((size_t)sind[b] * P_ + p) * ENC_ + tid * 8;
  float4 a = *(const float4*)src;
  float4 c = *(const float4*)(src + 4);
  bf16x8 v;
  v[0] = f2b(a.x); v[1] = f2b(a.y); v[2] = f2b(a.z); v[3] = f2b(a.w);
  v[4] = f2b(c.x); v[5] = f2b(c.y); v[6] = f2b(c.z); v[7] = f2b(c.w);
  *(bf16x8*)(encb + (size_t)mg * ENC_ + tid * 8) = v;
  size_t off = (((size_t)(mg >> 4) * 64 + (tid >> 2)) << 9) +
               (((mg & 15) | ((tid & 3) << 4)) << 3);
  *(bf16x8*)(encbt + off) = v;
}

// enc mean -> g_em (bf16), grid (64, 4): 512-col chunks
__global__ __launch_bounds__(64) void k_encmeanb(const short* __restrict__ encb,
                                                 short* __restrict__ em) {
  int b = blockIdx.x;
  int col0 = blockIdx.y * 512 + threadIdx.x * 8;
  const short* src = encb + (size_t)b * P_ * ENC_ + col0;
  float acc[8] = {};
  for (int p = 0; p < P_; ++p) {
    bf16x8 v = *(const bf16x8*)(src + (size_t)p * ENC_);
#pragma unroll
    for (int j = 0; j < 8; ++j) acc[j] += b2f(v[j]);
  }
#pragma unroll
  for (int j = 0; j < 8; ++j) em[b * 2048 + col0 + j] = f2b(acc[j] * (1.0f / 196.0f));
}

// prefill xemb[t][b] = emb table row of caps[b][t]
__global__ __launch_bounds__(256) void k_prefill(const float* __restrict__ emb,
                                                 const int* __restrict__ caps_s,
                                                 short* __restrict__ xemb) {
  int t = blockIdx.x, b = blockIdx.y, tid = threadIdx.x;  // (19, 64)
  short* xr = xemb + ((size_t)t * 64 + b) * 1024;
  int cap = caps_s[b * MAXLEN_ + t];
  int j = tid * 4;
  float4 v = *(const float4*)(emb + (size_t)cap * 1024 + j);
  short4 o;
  o.x = f2b(v.x); o.y = f2b(v.y); o.z = f2b(v.z); o.w = f2b(v.w);
  *(short4*)(xr + j) = o;
}

// ---------------- fused weight converts: all 10 jobs, wave-per-tile, coalesced 1KB writes ----------------
struct F2BJobs {
  const float* src[10];
  short* dst[10];
  int kstride[10];
  int c0[10];
  int ncols[10];
  int ktot[10];
  int koff[10];
  int base[11];  // cumulative block offsets (1 block = 4 tiles = 2048 elems)
};

__global__ __launch_bounds__(256) void k_f2bt_all(F2BJobs jb) {
  int bg = blockIdx.x;
  int j = 0;
#pragma unroll
  for (int q = 1; q < 10; ++q)
    if (bg >= jb.base[q]) j = q;
  int wave = threadIdx.x >> 6, lane = threadIdx.x & 63;
  int tau = (bg - jb.base[j]) * 4 + wave;       // tile index within job
  int ntk = jb.ncols[j] >> 5;                    // k-tiles per row-group (job-local)
  int rt = tau / ntk, kt = tau - rt * ntk;
  int r = rt * 16 + (lane & 15);                 // source row
  int k8 = kt * 32 + (lane >> 4) * 8;            // source k (job-local)
  const float* s = jb.src[j] + (size_t)r * jb.kstride[j] + jb.c0[j] + k8;
  float4 a = *(const float4*)s;
  float4 c = *(const float4*)(s + 4);
  bf16x8 v;
  v[0] = f2b(a.x); v[1] = f2b(a.y); v[2] = f2b(a.z); v[3] = f2b(a.w);
  v[4] = f2b(c.x); v[5] = f2b(c.y); v[6] = f2b(c.z); v[7] = f2b(c.w);
  int kg0 = jb.koff[j] + kt * 32;                // global k of tile start
  size_t toff = (((size_t)rt * (jb.ktot[j] >> 5) + (kg0 >> 5)) << 9);
  *(bf16x8*)(jb.dst[j] + toff + lane * 8) = v;   // wave writes one contiguous 1KB tile
}

// ---------------- att1 = enc @ We^T + be -> bf16 (12544x1024), both TILED ----------------
// Round-10 measured-best config: 512 thr, wave = 4mt x 4nt, block 128x256, grid (98,4), no swizzle
__global__ __launch_bounds__(512) void k_att1_t(const short* __restrict__ At,
                                                const short* __restrict__ Wt,
                                                const float* __restrict__ be,
                                                short* __restrict__ Cb) {
  int wave = threadIdx.x >> 6, lane = threadIdx.x & 63;
  int mt0 = blockIdx.x * 8 + (wave >> 2) * 4;
  int nt0 = blockIdx.y * 16 + (wave & 3) * 4;
  f32x4 acc[4][4] = {};
  const short* Ab = At + ((size_t)mt0 * 64 << 9) + lane * 8;  // ntk = 64
  const short* Wb = Wt + ((size_t)nt0 * 64 << 9) + lane * 8;
  for (int kt = 0; kt < 64; ++kt) {
    bf16x8 a[4], b[4];
#pragma unroll
    for (int i = 0; i < 4; ++i) a[i] = *(const bf16x8*)(Ab + (((size_t)i * 64 + kt) << 9));
#pragma unroll
    for (int j = 0; j < 4; ++j) b[j] = *(const bf16x8*)(Wb + (((size_t)j * 64 + kt) << 9));
#pragma unroll
    for (int i = 0; i < 4; ++i)
#pragma unroll
      for (int j = 0; j < 4; ++j)
        acc[i][j] = __builtin_amdgcn_mfma_f32_16x16x32_bf16(a[i], b[j], acc[i][j], 0, 0, 0);
  }
  int rr = (lane >> 4) * 4, cc = lane & 15;
  int m0 = mt0 * 16, n0 = nt0 * 16;
#pragma unroll
  for (int i = 0; i < 4; ++i)
#pragma unroll
    for (int j = 0; j < 4; ++j) {
      int n = n0 + j * 16 + cc;
      float bn = be[n];
#pragma unroll
      for (int r = 0; r < 4; ++r) {
        int m = m0 + i * 16 + rr + r;
        Cb[(size_t)m * 1024 + n] = f2b(acc[i][j][r] + bn);
      }
    }
}

// ---------------- skinny MFMA GEMM, tiled W: part[s][64][N] ----------------
__global__ __launch_bounds__(256) void k_skinny_t(const short* __restrict__ A, int lda,
                                                  const short* __restrict__ Wt, int ldw,
                                                  int N, int kchunk, float* __restrict__ part) {
  int wave = threadIdx.x >> 6, lane = threadIdx.x & 63;
  int n0 = blockIdx.x * 128 + wave * 32;
  int kb = blockIdx.y * kchunk;
  int lr = lane & 15, lk = (lane >> 4) * 8;
  int ntk = ldw >> 5;
  int nt0 = n0 >> 4;
  f32x4 acc[4][2] = {};
  const short* Ab = A + (size_t)lr * lda + kb + lk;
  const short* Wb0 = Wt + (((size_t)nt0 * ntk + (kb >> 5)) << 9) + lane * 8;
  const short* Wb1 = Wt + (((size_t)(nt0 + 1) * ntk + (kb >> 5)) << 9) + lane * 8;
  int nkt = kchunk >> 5;
  for (int kt = 0; kt < nkt; ++kt) {
    bf16x8 a[4], b0, b1;
#pragma unroll
    for (int i = 0; i < 4; ++i) a[i] = *(const bf16x8*)(Ab + (size_t)i * 16 * lda + kt * 32);
    b0 = *(const bf16x8*)(Wb0 + ((size_t)kt << 9));
    b1 = *(const bf16x8*)(Wb1 + ((size_t)kt << 9));
#pragma unroll
    for (int i = 0; i < 4; ++i) {
      acc[i][0] = __builtin_amdgcn_mfma_f32_16x16x32_bf16(a[i], b0, acc[i][0], 0, 0, 0);
      acc[i][1] = __builtin_amdgcn_mfma_f32_16x16x32_bf16(a[i], b1, acc[i][1], 0, 0, 0);
    }
  }
  float* po = part + (size_t)blockIdx.y * 64 * N;
  int rr = (lane >> 4) * 4, cc = lane & 15;
#pragma unroll
  for (int i = 0; i < 4; ++i)
#pragma unroll
    for (int j = 0; j < 2; ++j) {
      int n = n0 + j * 16 + cc;
#pragma unroll
      for (int r = 0; r < 4; ++r) {
        int m = i * 16 + rr + r;
        po[(size_t)m * N + n] = acc[i][j][r];
      }
    }
}

// sum nsplit partial planes into dst (64*4096 elems)
__global__ void k_sumn(const float* __restrict__ part, int nsplit, float* __restrict__ dst) {
  int idx = blockIdx.x * 256 + threadIdx.x;
  float s = 0.0f;
  for (int q = 0; q < nsplit; ++q) s += part[(size_t)q * 64 * 4096 + idx];
  dst[idx] = s;
}

// ---------------- batched emb GEMM: preemb[t][64][4096] = xemb[t] @ Wemb^T (K=1024) ----------------
// 1-D grid 304 = 8*38, XCD-chunk swizzle: XCD owns 2 W n-slices x all 19 t.
__global__ __launch_bounds__(256) void k_mid_emb4(const short* __restrict__ xemb,
                                                  const short* __restrict__ Wt,
                                                  float* __restrict__ preemb) {
  int wg = blockIdx.x;               // 304 = 8 * 38
  wg = (wg & 7) * 38 + (wg >> 3);
  int t = wg % 19;
  int nch = wg / 19;                 // [0,16)
  const short* A = xemb + (size_t)t * 64 * 1024;
  int wave = threadIdx.x >> 6, lane = threadIdx.x & 63;
  int nt0 = nch * 16 + wave * 4;  // 256 n-tiles total
  int lr = lane & 15, lk = (lane >> 4) * 8;
  f32x4 acc[4][4] = {};
  const short* Ab = A + (size_t)lr * 1024 + lk;
  const short* Wb[4];
#pragma unroll
  for (int j = 0; j < 4; ++j) Wb[j] = Wt + ((size_t)(nt0 + j) * 32 << 9) + lane * 8;
  for (int kt = 0; kt < 32; ++kt) {
    bf16x8 a[4], b[4];
#pragma unroll
    for (int j = 0; j < 4; ++j) b[j] = *(const bf16x8*)(Wb[j] + ((size_t)kt << 9));
#pragma unroll
    for (int i = 0; i < 4; ++i) a[i] = *(const bf16x8*)(Ab + (size_t)i * 16 * 1024 + kt * 32);
#pragma unroll
    for (int i = 0; i < 4; ++i)
#pragma unroll
      for (int j = 0; j < 4; ++j)
        acc[i][j] = __builtin_amdgcn_mfma_f32_16x16x32_bf16(a[i], b[j], acc[i][j], 0, 0, 0);
  }
  float* po = preemb + (size_t)t * 64 * 4096;
  int rr = (lane >> 4) * 4, cc = lane & 15;
#pragma unroll
  for (int i = 0; i < 4; ++i)
#pragma unroll
    for (int j = 0; j < 4; ++j) {
      int n = (nt0 + j) * 16 + cc;
#pragma unroll
      for (int r = 0; r < 4; ++r) {
        int m = i * 16 + rr + r;
        po[(size_t)m * 4096 + n] = acc[i][j][r];
      }
    }
}

// ---------------- LSTM gates: biases + nsplit partials (+ pre, pre2), update c, forward h ----------------
__global__ void k_gates(const float* __restrict__ part, int nsplit,
                        const float* __restrict__ pre, const float* __restrict__ pre2,
                        const float* __restrict__ bih, const float* __restrict__ bhh,
                        float* __restrict__ c,
                        const short* __restrict__ hold, int ldo,
                        short* __restrict__ dst1, int ld1,
                        short* __restrict__ dst2, int ld2,
                        const int* __restrict__ declen, int t) {
  int idx = blockIdx.x * 256 + threadIdx.x;  // 65536
  int b = idx >> 10, j = idx & 1023;
  const float* pb = part + (size_t)b * 4096;
  float gi = bih[j] + bhh[j];
  float gf = bih[1024 + j] + bhh[1024 + j];
  float gg = bih[2048 + j] + bhh[2048 + j];
  float go = bih[3072 + j] + bhh[3072 + j];
  if (pre) {
    const float* pp = pre + (size_t)b * 4096;
    gi += pp[j]; gf += pp[j + 1024]; gg += pp[j + 2048]; go += pp[j + 3072];
  }
  if (pre2) {
    const float* pp = pre2 + (size_t)b * 4096;
    gi += pp[j]; gf += pp[j + 1024]; gg += pp[j + 2048]; go += pp[j + 3072];
  }
  for (int s = 0; s < nsplit; ++s) {
    const float* p = pb + (size_t)s * 64 * 4096;
    gi += p[j]; gf += p[j + 1024]; gg += p[j + 2048]; go += p[j + 3072];
  }
  float si = 1.0f / (1.0f + expf(-gi));
  float sf = 1.0f / (1.0f + expf(-gf));
  float so = 1.0f / (1.0f + expf(-go));
  float cn = sf * c[idx] + si * tanhf(gg);
  float hn = so * tanhf(cn);
  short hb;
  if (t < declen[b]) {
    c[idx] = cn;
    hb = f2b(hn);
  } else {
    hb = hold[b * ldo + j];
  }
  dst1[b * ld1 + j] = hb;
  dst2[b * ld2 + j] = hb;
}

// ---------------- e[b,p] = Wf . relu(att1[b,p,:] + att2) + bf ; 16 p per block ----------------
__global__ __launch_bounds__(256) void k_e(const short* __restrict__ att1,
                                           const float* __restrict__ att2p,
                                           const float* __restrict__ bd,
                                           const float* __restrict__ Wf,
                                           const float* __restrict__ bf,
                                           float* __restrict__ e) {
  __shared__ float a2[1024];
  int b = blockIdx.x / 13, pq = blockIdx.x % 13;  // 13 chunks of 16 p
  for (int i = threadIdx.x; i < 1024; i += 256) {
    float s = bd[i];
#pragma unroll
    for (int q = 0; q < 4; ++q) s += att2p[q * 65536 + b * 1024 + i];
    a2[i] = s;
  }
  __syncthreads();
  int wave = threadIdx.x >> 6, lane = threadIdx.x & 63;
#pragma unroll
  for (int i = 0; i < 4; ++i) {
    int p = pq * 16 + wave * 4 + i;
    if (p >= P_) break;
    const short* a1 = att1 + ((size_t)(b * P_ + p)) * 1024;
    float s = 0.0f;
#pragma unroll
    for (int h = 0; h < 2; ++h) {
      int k0 = lane * 8 + h * 512;
      bf16x8 v = *(const bf16x8*)(a1 + k0);
#pragma unroll
      for (int j = 0; j < 8; ++j) s += Wf[k0 + j] * fmaxf(b2f(v[j]) + a2[k0 + j], 0.0f);
    }
#pragma unroll
    for (int off = 32; off; off >>= 1) s += __shfl_down(s, off);
    if (lane == 0) e[b * P_ + p] = s + bf[0];
  }
}

// ---------------- softmax (in-block) + awe, grid (64, 8) ----------------
__global__ __launch_bounds__(256) void k_sawe(const float* __restrict__ e,
                                              const short* __restrict__ encb,
                                              short* __restrict__ xc2t) {
  int b = blockIdx.x, ch = blockIdx.y;  // ch < 8
  __shared__ float al[P_];
  __shared__ float red[8][256];
  int tid = threadIdx.x;
  if (tid < 64) {
    float vals[4];
    float mx = -1e30f;
#pragma unroll
    for (int q = 0; q < 4; ++q) {
      int p = tid + q * 64;
      vals[q] = (p < P_) ? e[b * P_ + p] : -1e30f;
      mx = fmaxf(mx, vals[q]);
    }
#pragma unroll
    for (int off = 32; off; off >>= 1) mx = fmaxf(mx, __shfl_xor(mx, off));
    float sum = 0.0f;
#pragma unroll
    for (int q = 0; q < 4; ++q) {
      int p = tid + q * 64;
      vals[q] = (p < P_) ? expf(vals[q] - mx) : 0.0f;
      sum += vals[q];
    }
#pragma unroll
    for (int off = 32; off; off >>= 1) sum += __shfl_xor(sum, off);
    float inv = 1.0f / sum;
#pragma unroll
    for (int q = 0; q < 4; ++q) {
      int p = tid + q * 64;
      if (p < P_) al[p] = vals[q] * inv;
    }
  }
  __syncthreads();
  int pg = tid >> 5, cg = tid & 31;
  int col = ch * 256 + cg * 8;
  const short* src = encb + (size_t)b * P_ * ENC_ + col;
  float acc[8] = {};
  for (int p = pg; p < P_; p += 8) {
    bf16x8 v = *(const bf16x8*)(src + (size_t)p * ENC_);
    float ap = al[p];
#pragma unroll
    for (int j = 0; j < 8; ++j) acc[j] += ap * b2f(v[j]);
  }
#pragma unroll
  for (int j = 0; j < 8; ++j) red[pg][cg * 8 + j] = acc[j];
  __syncthreads();
  float s = 0.0f;
#pragma unroll
  for (int g = 0; g < 8; ++g) s += red[g][tid];
  xc2t[b * 4096 + ch * 256 + tid] = f2b(s);
}

// ---------------- batched head GEMM: 4 nt per wave, 1-D grid 760 = 8*95 XCD-chunked ----------------
__global__ __launch_bounds__(256) void k_head4(const short* __restrict__ Aall,
                                               const short* __restrict__ Wt,
                                               const float* __restrict__ bias,
                                               float* __restrict__ outp,
                                               const int* __restrict__ declen) {
  int wg = blockIdx.x;               // 760 = 8 * 95
  wg = (wg & 7) * 95 + (wg >> 3);
  int t = wg % 19;
  int nch = wg / 19;                 // [0,40)
  const short* A = Aall + (size_t)t * (64 * 4096);
  int wave = threadIdx.x >> 6, lane = threadIdx.x & 63;
  int nt0 = nch * 16 + wave * 4;     // 4 n-tiles per wave; 625 total
  int lr = lane & 15, lk = (lane >> 4) * 8;
  f32x4 acc[4][4] = {};
  const short* Ab = A + (size_t)lr * 4096 + lk;
  const short* Wb[4];
  bool ok[4];
#pragma unroll
  for (int j = 0; j < 4; ++j) {
    ok[j] = (nt0 + j) < (V_ >> 4);
    Wb[j] = Wt + ((size_t)(ok[j] ? nt0 + j : 0) * 32 << 9) + lane * 8;
  }
  for (int kt = 0; kt < 32; ++kt) {
    bf16x8 a[4], b[4];
#pragma unroll
    for (int j = 0; j < 4; ++j) b[j] = *(const bf16x8*)(Wb[j] + ((size_t)kt << 9));
#pragma unroll
    for (int i = 0; i < 4; ++i) a[i] = *(const bf16x8*)(Ab + (size_t)i * 16 * 4096 + kt * 32);
#pragma unroll
    for (int i = 0; i < 4; ++i)
#pragma unroll
      for (int j = 0; j < 4; ++j)
        acc[i][j] = __builtin_amdgcn_mfma_f32_16x16x32_bf16(a[i], b[j], acc[i][j], 0, 0, 0);
  }
  int rr = (lane >> 4) * 4, cc = lane & 15;
#pragma unroll
  for (int j = 0; j < 4; ++j) {
    if (!ok[j]) continue;
    int n = (nt0 + j) * 16 + cc;
    float bn = bias[n];
#pragma unroll
    for (int i = 0; i < 4; ++i) {
#pragma unroll
      for (int r = 0; r < 4; ++r) {
        int b = i * 16 + rr + r;
        float val = acc[i][j][r] + bn;
        outp[((size_t)b * TDEC_ + t) * V_ + n] = (t < declen[b]) ? val : 0.0f;
      }
    }
  }
}

// ---------------- host ----------------
extern "C" void kernel_launch(void* const* d_in, const int* in_sizes, int n_in,
                              void* d_out, int out_size, void* d_ws, size_t ws_size,
                              hipStream_t stream) {
  (void)in_sizes; (void)n_in; (void)d_ws; (void)ws_size; (void)out_size;
  const float* enc  = (const float*)d_in[0];
  const int*   caps = (const int*)d_in[1];
  const int*   cl   = (const int*)d_in[2];
  const float* emb  = (const float*)d_in[3];
  const float* We   = (const float*)d_in[4];
  const float* be   = (const float*)d_in[5];
  const float* Wd   = (const float*)d_in[6];
  const float* bd   = (const float*)d_in[7];
  const float* Wf   = (const float*)d_in[8];
  const float* bf   = (const float*)d_in[9];
  const float* Wih1 = (const float*)d_in[10];
  const float* Whh1 = (const float*)d_in[11];
  const float* bih1 = (const float*)d_in[12];
  const float* bhh1 = (const float*)d_in[13];
  const float* Wih2 = (const float*)d_in[14];
  const float* Whh2 = (const float*)d_in[15];
  const float* bih2 = (const float*)d_in[16];
  const float* bhh2 = (const float*)d_in[17];
  const float* Wfc1 = (const float*)d_in[18];
  const float* bfc1 = (const float*)d_in[19];
  const float* Wfc  = (const float*)d_in[20];
  const float* bfc  = (const float*)d_in[21];
  float* out = (float*)d_out;

  short *encb, *encbt, *att1, *Wp1t, *Wemt, *Wembt, *Wc2t, *Webt, *Wdt, *Wfc1t, *Wfct;
  short *xs1, *xemb, *xc2, *em;
  float *preemb, *preem, *part, *att2p, *e, *c1, *c2;
  int* ib;
  hipGetSymbolAddress((void**)&encb, HIP_SYMBOL(g_encb));
  hipGetSymbolAddress((void**)&encbt, HIP_SYMBOL(g_encbt));
  hipGetSymbolAddress((void**)&att1, HIP_SYMBOL(g_att1));
  hipGetSymbolAddress((void**)&Wp1t, HIP_SYMBOL(g_Wp1t));
  hipGetSymbolAddress((void**)&Wemt, HIP_SYMBOL(g_Wemt));
  hipGetSymbolAddress((void**)&Wembt, HIP_SYMBOL(g_Wembt));
  hipGetSymbolAddress((void**)&Wc2t, HIP_SYMBOL(g_Wc2t));
  hipGetSymbolAddress((void**)&Webt, HIP_SYMBOL(g_Webt));
  hipGetSymbolAddress((void**)&Wdt, HIP_SYMBOL(g_Wdt));
  hipGetSymbolAddress((void**)&Wfc1t, HIP_SYMBOL(g_Wfc1t));
  hipGetSymbolAddress((void**)&Wfct, HIP_SYMBOL(g_Wfct));
  hipGetSymbolAddress((void**)&xs1, HIP_SYMBOL(g_xs1));
  hipGetSymbolAddress((void**)&xemb, HIP_SYMBOL(g_xemb));
  hipGetSymbolAddress((void**)&xc2, HIP_SYMBOL(g_xc2));
  hipGetSymbolAddress((void**)&em, HIP_SYMBOL(g_em));
  hipGetSymbolAddress((void**)&preemb, HIP_SYMBOL(g_preemb));
  hipGetSymbolAddress((void**)&preem, HIP_SYMBOL(g_preem));
  hipGetSymbolAddress((void**)&part, HIP_SYMBOL(g_part));
  hipGetSymbolAddress((void**)&att2p, HIP_SYMBOL(g_att2p));
  hipGetSymbolAddress((void**)&e, HIP_SYMBOL(g_e));
  hipGetSymbolAddress((void**)&c1, HIP_SYMBOL(g_c1));
  hipGetSymbolAddress((void**)&c2, HIP_SYMBOL(g_c2));
  hipGetSymbolAddress((void**)&ib, HIP_SYMBOL(g_ibuf));
  int* sind = ib;
  int* declen = ib + 64;
  int* caps_s = ib + 128;

  float* out_preds  = out;
  float* out_preds1 = out + (size_t)B_ * TDEC_ * V_;
  float* out_caps   = out + 2ull * B_ * TDEC_ * V_;
  float* out_declen = out_caps + B_ * MAXLEN_;
  float* out_sind   = out_declen + B_;

  // ---- preprocessing ----
  k_sort<<<1, 64, 0, stream>>>(cl, caps, sind, declen, caps_s, out_caps, out_declen, out_sind);
  hipMemsetAsync(c1, 0, 64 * 1024 * sizeof(float), stream);
  hipMemsetAsync(c2, 0, 64 * 1024 * sizeof(float), stream);
  hipMemsetAsync(xs1, 0, (size_t)64 * 2048 * sizeof(short), stream);  // t=0
  hipMemsetAsync(xc2, 0, (size_t)64 * 4096 * sizeof(short), stream);  // t=0
  k_encprep<<<12544, 256, 0, stream>>>(enc, sind, encb, encbt);
  k_encmeanb<<<dim3(64, 4), 64, 0, stream>>>(encb, em);
  k_prefill<<<dim3(19, 64), 256, 0, stream>>>(emb, caps_s, xemb);
  // fused weight converts (10 jobs, one launch, wave-per-tile)
  {
    F2BJobs jb;
    const float* srcs[10] = {Wih1, Whh1, Wih1, Wih1, Wih2, Whh2, We, Wd, Wfc1, Wfc};
    short* dsts[10] = {Wp1t, Wp1t, Wemt, Wembt, Wc2t, Wc2t, Webt, Wdt, Wfc1t, Wfct};
    int kstride[10] = {4096, 1024, 4096, 4096, 3072, 1024, 2048, 1024, 1024, 1024};
    int c0s[10]     = {0, 0, 1024, 3072, 0, 0, 0, 0, 0, 0};
    int ncols[10]   = {1024, 1024, 2048, 1024, 3072, 1024, 2048, 1024, 1024, 1024};
    int ktots[10]   = {2048, 2048, 2048, 1024, 4096, 4096, 2048, 1024, 1024, 1024};
    int koffs[10]   = {0, 1024, 0, 0, 0, 3072, 0, 0, 0, 0};
    int nblk[10]    = {2048, 2048, 4096, 2048, 6144, 2048, 1024, 512, 5000, 5000};
    int cum = 0;
    for (int q = 0; q < 10; ++q) {
      jb.src[q] = srcs[q]; jb.dst[q] = dsts[q];
      jb.kstride[q] = kstride[q]; jb.c0[q] = c0s[q]; jb.ncols[q] = ncols[q];
      jb.ktot[q] = ktots[q]; jb.koff[q] = koffs[q];
      jb.base[q] = cum; cum += nblk[q];
    }
    jb.base[10] = cum;  // 29968
    k_f2bt_all<<<cum, 256, 0, stream>>>(jb);
  }
  k_att1_t<<<dim3(98, 4), 512, 0, stream>>>(encbt, Webt, be, att1);
  // em contribution to LSTM1 gates (once): em @ Wem^T, KS=4, then sum
  k_skinny_t<<<dim3(32, 4), 256, 0, stream>>>(em, 2048, Wemt, 2048, 4096, 512, part);
  k_sumn<<<1024, 256, 0, stream>>>(part, 4, preem);
  // emb contribution per t (batched)
  k_mid_emb4<<<304, 256, 0, stream>>>(xemb, Wembt, preemb);

  // ---- decode loop ----
  for (int t = 0; t < TDEC_; ++t) {
    short* s1t = xs1 + (size_t)t * 64 * 2048;
    short* s1n = xs1 + (size_t)(t + 1) * 64 * 2048;
    short* x2t = xc2 + (size_t)t * 64 * 4096;
    short* x2n = xc2 + (size_t)(t + 1) * 64 * 4096;
    // LSTM1 step: [h2|h1] @ Wp1^T  (K=2048, KS=8 -> 256)
    k_skinny_t<<<dim3(32, 8), 256, 0, stream>>>(s1t, 2048, Wp1t, 2048, 4096, 256, part);
    k_gates<<<256, 256, 0, stream>>>(part, 8, preemb + (size_t)t * 64 * 4096, preem,
                                     bih1, bhh1, c1, s1t + 1024, 2048,
                                     s1n + 1024, 2048, x2t + 2048, 4096, declen, t);
    // att2 = h1 @ Wd^T  (K=1024, KS=4 -> 256)
    k_skinny_t<<<dim3(8, 4), 256, 0, stream>>>(x2t + 2048, 4096, Wdt, 1024, 1024, 256, att2p);
    k_e<<<832, 256, 0, stream>>>(att1, att2p, bd, Wf, bf, e);
    k_sawe<<<dim3(64, 8), 256, 0, stream>>>(e, encb, x2t);
    // LSTM2: [awe|h1|h2] @ Wc2^T  (K=4096, KS=8 -> 512)
    k_skinny_t<<<dim3(32, 8), 256, 0, stream>>>(x2t, 4096, Wc2t, 4096, 4096, 512, part);
    k_gates<<<256, 256, 0, stream>>>(part, 8, nullptr, nullptr, bih2, bhh2, c2, s1t, 2048,
                                     s1n, 2048, x2n + 3072, 4096, declen, t);
  }
  // ---- batched output heads over all t ----
  k_head4<<<760, 256, 0, stream>>>(xc2 + 2048, Wfc1t, bfc1, out_preds1, declen);
  k_head4<<<760, 256, 0, stream>>>(xc2 + 64 * 4096 + 3072, Wfct, bfc, out_preds, declen);
}